// Round 1
// baseline (273.110 us; speedup 1.0000x reference)
//
#include <hip/hip_runtime.h>
#include <math.h>

#define Bn 64
#define Sn 512
#define Hn 768
#define Mn 512
#define Tn 26
#define TP 32   // padded tag dim

// ws layout (floats)
#define OFF_WCT 0                       // Wct[h][c] : 768 x 32
#define OFF_BC  (Hn*TP)                 // 24576 : bc[32]
#define OFF_E0  (OFF_BC + TP)           // 24608 : E0[b][s][32]
#define ESZ     ((size_t)Bn*Sn*TP)      // 1048576
#define OFF_E1  (OFF_E0 + ESZ)
#define OFF_LLH (OFF_E1 + ESZ)          // llh[64]

// ---------------- Kernel A: Wc = W2@W1 (26x768), bc = W2@b1 + b2 ----------------
__global__ __launch_bounds__(256) void k_prep(const float* __restrict__ W1,
                                              const float* __restrict__ b1,
                                              const float* __restrict__ W2,
                                              const float* __restrict__ b2,
                                              float* __restrict__ ws) {
    int gid = blockIdx.x * 256 + threadIdx.x;   // 96 blocks * 256 = 24576 = 32*768
    int c = gid / Hn, h = gid % Hn;
    if (c < TP) {
        float acc = 0.f;
        if (c < Tn) {
            for (int m = 0; m < Mn; ++m)
                acc = fmaf(W2[c * Mn + m], W1[(size_t)m * Hn + h], acc);
        }
        ws[OFF_WCT + (size_t)h * TP + c] = acc;
    }
    if (gid < TP) {
        float acc = 0.f;
        if (gid < Tn) {
            acc = b2[gid];
            for (int m = 0; m < Mn; ++m) acc = fmaf(W2[gid * Mn + m], b1[m], acc);
        }
        ws[OFF_BC + gid] = acc;
    }
}

// ---------------- Kernel B: emissions = hidden @ Wct + bc (K split in 2) ----------------
// 256 blocks: rb = bx>>1 (row block of 256 rows), ks = bx&1 (K half).
// A-tile staged transposed in LDS: At[kk][row], row stride 260 -> conflict-free reads.
__global__ __launch_bounds__(256) void k_emis(const float* __restrict__ hidden,
                                              const float* __restrict__ ws,
                                              float* __restrict__ Ebase) {
    __shared__ float At[32][260];
    const int tid = threadIdx.x;
    const int bx  = blockIdx.x;
    const int rb  = bx >> 1;
    const int ks  = bx & 1;
    const int row0 = rb * 256;
    const int k0b  = ks * 384;

    float acc[Tn];
#pragma unroll
    for (int c = 0; c < Tn; ++c) acc[c] = 0.f;

    for (int kc = 0; kc < 12; ++kc) {
        const int k0 = k0b + kc * 32;
        __syncthreads();
        // stage 256 rows x 32 k (coalesced float4 loads, transposed store)
#pragma unroll
        for (int j = 0; j < 8; ++j) {
            int idx = j * 256 + tid;          // float4 index within tile
            int r = idx >> 3, k4 = (idx & 7) * 4;
            float4 v = *reinterpret_cast<const float4*>(
                hidden + (size_t)(row0 + r) * Hn + k0 + k4);
            At[k4 + 0][r] = v.x; At[k4 + 1][r] = v.y;
            At[k4 + 2][r] = v.z; At[k4 + 3][r] = v.w;
        }
        __syncthreads();
        const float* wrow = ws + OFF_WCT + (size_t)k0 * TP;
#pragma unroll 4
        for (int kk = 0; kk < 32; ++kk) {
            float a = At[kk][tid];            // own row, conflict-free
#pragma unroll
            for (int c = 0; c < Tn; ++c)
                acc[c] = fmaf(a, wrow[kk * TP + c], acc[c]);   // uniform -> s_load
        }
    }

    float tmp[TP];
#pragma unroll
    for (int c = 0; c < Tn; ++c) tmp[c] = acc[c];
#pragma unroll
    for (int c = Tn; c < TP; ++c) tmp[c] = 0.f;
    if (ks == 0) {
#pragma unroll
        for (int c = 0; c < Tn; ++c) tmp[c] += ws[OFF_BC + c];
    }
    float* dst = Ebase + (size_t)ks * ESZ + (size_t)(row0 + tid) * TP;
#pragma unroll
    for (int j = 0; j < 8; ++j)
        *reinterpret_cast<float4*>(dst + j * 4) =
            make_float4(tmp[4*j], tmp[4*j+1], tmp[4*j+2], tmp[4*j+3]);
}

// ---------------- Kernel C: per-batch CRF forward scan + numerator ----------------
__global__ __launch_bounds__(64) void k_crf(const float* __restrict__ ws,
                                            const float* __restrict__ start_t,
                                            const float* __restrict__ end_t,
                                            const float* __restrict__ trans,
                                            const int* __restrict__ labels,
                                            const int* __restrict__ lengths,
                                            float* __restrict__ llh) {
    const int b = blockIdx.x;
    const int lane = threadIdx.x;
    const int len = lengths[b];
    const float* E0 = ws + OFF_E0;
    const float* E1 = ws + OFF_E1;
    const size_t rowb = (size_t)b * Sn;

    // ---- numerator (vectorized over s across lanes) ----
    float part = 0.f;
    for (int s = 1 + lane; s < len; s += 64) {
        int lp = labels[rowb + s - 1];
        int lc = labels[rowb + s];
        size_t ei = (rowb + s) * TP + lc;
        part += trans[lp * Tn + lc] + E0[ei] + E1[ei];
    }
#pragma unroll
    for (int off = 32; off; off >>= 1) part += __shfl_xor(part, off);
    int l0 = labels[rowb];
    int ll = labels[rowb + len - 1];
    size_t e0i = rowb * TP + l0;
    float numer = part + start_t[l0] + E0[e0i] + E1[e0i] + end_t[ll];

    // ---- preload exp(trans) column for this lane's tag ----
    const int t = lane;
    float etr[Tn];
#pragma unroll
    for (int i = 0; i < Tn; ++i)
        etr[i] = (t < Tn) ? __expf(trans[i * Tn + t]) : 0.f;

    // ---- alpha init ----
    float alpha;
    if (t < Tn) {
        size_t ei = rowb * TP + t;
        alpha = start_t[t] + E0[ei] + E1[ei];
    } else alpha = -INFINITY;

    const int tc = t & 31;
    float em0 = 0.f, em1 = 0.f;
    if (len > 1) {
        size_t ei = (rowb + 1) * TP + tc;
        em0 = E0[ei]; em1 = E1[ei];
    }
    for (int s = 1; s < len; ++s) {
        float emit = em0 + em1;
        if (s + 1 < len) {   // prefetch next step's emissions
            size_t ei = (rowb + s + 1) * TP + tc;
            em0 = E0[ei]; em1 = E1[ei];
        }
        float C = __uint_as_float(__builtin_amdgcn_readfirstlane(__float_as_uint(alpha)));
        float e = __expf(alpha - C);
        float sum = 0.f;
#pragma unroll
        for (int i = 0; i < Tn; ++i) {
            float eb = __uint_as_float(__builtin_amdgcn_readlane(__float_as_uint(e), i));
            sum = fmaf(eb, etr[i], sum);
        }
        float na = C + __logf(sum) + emit;
        alpha = (t < Tn) ? na : -INFINITY;
    }

    // ---- denominator = logsumexp(alpha + end_trans) over 26 tags ----
    float av = (t < Tn) ? alpha + end_t[t] : -INFINITY;
    float mx = av;
#pragma unroll
    for (int off = 16; off; off >>= 1) mx = fmaxf(mx, __shfl_xor(mx, off));
    float se = (t < Tn) ? __expf(av - mx) : 0.f;
#pragma unroll
    for (int off = 16; off; off >>= 1) se += __shfl_xor(se, off);
    float denom = mx + __logf(se);
    if (lane == 0) llh[b] = numer - denom;
}

// ---------------- Kernel D: out = -mean(llh) ----------------
__global__ __launch_bounds__(64) void k_out(const float* __restrict__ llh,
                                            float* __restrict__ out) {
    float v = llh[threadIdx.x];
#pragma unroll
    for (int off = 32; off; off >>= 1) v += __shfl_xor(v, off);
    if (threadIdx.x == 0) out[0] = -v * (1.0f / 64.0f);
}

extern "C" void kernel_launch(void* const* d_in, const int* in_sizes, int n_in,
                              void* d_out, int out_size, void* d_ws, size_t ws_size,
                              hipStream_t stream) {
    const float* hidden  = (const float*)d_in[0];
    const float* W1      = (const float*)d_in[1];
    const float* b1      = (const float*)d_in[2];
    const float* W2      = (const float*)d_in[3];
    const float* b2      = (const float*)d_in[4];
    const float* start_t = (const float*)d_in[5];
    const float* end_t   = (const float*)d_in[6];
    const float* trans   = (const float*)d_in[7];
    const int*   labels  = (const int*)d_in[8];
    const int*   lengths = (const int*)d_in[9];
    float* ws  = (float*)d_ws;
    float* out = (float*)d_out;

    hipLaunchKernelGGL(k_prep, dim3(96), dim3(256), 0, stream, W1, b1, W2, b2, ws);
    hipLaunchKernelGGL(k_emis, dim3(256), dim3(256), 0, stream, hidden, ws, ws + OFF_E0);
    hipLaunchKernelGGL(k_crf, dim3(64), dim3(64), 0, stream, ws, start_t, end_t, trans,
                       labels, lengths, ws + OFF_LLH);
    hipLaunchKernelGGL(k_out, dim3(1), dim3(64), 0, stream, ws + OFF_LLH, out);
}

// Round 2
// 183.766 us; speedup vs baseline: 1.4862x; 1.4862x over previous
//
#include <hip/hip_runtime.h>
#include <math.h>

#define Bn 64
#define Sn 512
#define Hn 768
#define Mn 512
#define Tn 26
#define TP 32   // padded tag dim in global Eexp

// ws layout (floats)
#define OFF_WCT 0                       // Wct[k][c] : 768 x 32
#define OFF_BC  (Hn*TP)                 // bc[32]
#define OFF_EX  (OFF_BC + TP)           // Eexp[b][s][32]
#define EXSZ    ((size_t)Bn*Sn*TP)
#define OFF_LLH (OFF_EX + EXSZ)         // llh[64]

// ---------------- Kernel A: Wc = W2@W1 (26x768), bc = W2@b1 + b2 ----------------
__global__ __launch_bounds__(256) void k_prep(const float* __restrict__ W1,
                                              const float* __restrict__ b1,
                                              const float* __restrict__ W2,
                                              const float* __restrict__ b2,
                                              float* __restrict__ ws) {
    int gid = blockIdx.x * 256 + threadIdx.x;   // 96 blocks * 256 = 24576 = 32*768
    int c = gid / Hn, h = gid % Hn;
    if (c < TP) {
        float acc = 0.f;
        if (c < Tn) {
            for (int m = 0; m < Mn; ++m)
                acc = fmaf(W2[c * Mn + m], W1[(size_t)m * Hn + h], acc);
        }
        ws[OFF_WCT + (size_t)h * TP + c] = acc;
    }
    if (gid < TP) {
        float acc = 0.f;
        if (gid < Tn) {
            acc = b2[gid];
            for (int m = 0; m < Mn; ++m) acc = fmaf(W2[gid * Mn + m], b1[m], acc);
        }
        ws[OFF_BC + gid] = acc;
    }
}

// ---------------- Kernel B: Eexp = exp(hidden @ Wct + bc) ----------------
// 256 blocks x 128 rows, K split between thread halves (h = tid>>7), merged via LDS.
// Register-staged double-buffered global->LDS (T14-style issue-early/write-late).
__global__ __launch_bounds__(256) void k_emis(const float* __restrict__ hidden,
                                              const float* __restrict__ ws,
                                              float* __restrict__ Eexp) {
    __shared__ float At[64][129];   // [k-in-chunk(both halves)][row], pad->conflict-free
    const int tid  = threadIdx.x;
    const int row0 = blockIdx.x * 128;
    const int r    = tid & 127;
    const int h    = __builtin_amdgcn_readfirstlane(threadIdx.x >> 7);
    const float* wct = ws + OFF_WCT;

    float4 v[8], v2[8];
#pragma unroll
    for (int j = 0; j < 8; ++j) {
        int id = tid + j * 256; int rr = id >> 4, k4q = id & 15;
        int kg = (k4q >> 3) * 384 + (k4q & 7) * 4;            // chunk 0
        v[j] = *reinterpret_cast<const float4*>(hidden + (size_t)(row0 + rr) * Hn + kg);
    }

    float acc[Tn];
#pragma unroll
    for (int c = 0; c < Tn; ++c) acc[c] = 0.f;

    for (int kc = 0; kc < 12; ++kc) {
        __syncthreads();
#pragma unroll
        for (int j = 0; j < 8; ++j) {
            int id = tid + j * 256; int rr = id >> 4, k4q = id & 15;
            int rowb = (k4q >> 3) * 32 + (k4q & 7) * 4;
            float* p = &At[0][0] + rowb * 129 + rr;
            p[0] = v[j].x; p[129] = v[j].y; p[258] = v[j].z; p[387] = v[j].w;
        }
        __syncthreads();
        if (kc < 11) {
#pragma unroll
            for (int j = 0; j < 8; ++j) {
                int id = tid + j * 256; int rr = id >> 4, k4q = id & 15;
                int kg = (k4q >> 3) * 384 + (kc + 1) * 32 + (k4q & 7) * 4;
                v2[j] = *reinterpret_cast<const float4*>(hidden + (size_t)(row0 + rr) * Hn + kg);
            }
        }
        const float* wbase = wct + (size_t)(h * 384 + kc * 32) * TP;
#pragma unroll 2
        for (int kk = 0; kk < 32; ++kk) {
            float av = At[h * 32 + kk][r];
#pragma unroll
            for (int c = 0; c < Tn; ++c)
                acc[c] = fmaf(av, wbase[kk * TP + c], acc[c]);
        }
#pragma unroll
        for (int j = 0; j < 8; ++j) v[j] = v2[j];
    }

    __syncthreads();
    float* mb = &At[0][0];           // reuse as 128x26 merge buffer
    if (h == 1) {
#pragma unroll
        for (int c = 0; c < Tn; ++c) mb[r * Tn + c] = acc[c];
    }
    __syncthreads();
    if (h == 0) {
        float tmp[TP];
#pragma unroll
        for (int c = 0; c < Tn; ++c)
            tmp[c] = __expf(acc[c] + mb[r * Tn + c] + ws[OFF_BC + c]);
#pragma unroll
        for (int c = Tn; c < TP; ++c) tmp[c] = 0.f;
        float* dst = Eexp + (size_t)(row0 + r) * TP;
#pragma unroll
        for (int j = 0; j < 8; ++j)
            *reinterpret_cast<float4*>(dst + 4 * j) =
                make_float4(tmp[4*j], tmp[4*j+1], tmp[4*j+2], tmp[4*j+3]);
    }
}

// ---------------- Kernel C: per-batch CRF (linear-space scan, LDS-staged) ----------------
__device__ __forceinline__ float rl(float x, int i) {
    return __uint_as_float(__builtin_amdgcn_readlane(__float_as_uint(x), i));
}
__device__ __forceinline__ float matvec26(float a, const float* etr) {
    float n0 = 0.f, n1 = 0.f, n2 = 0.f, n3 = 0.f;
#pragma unroll
    for (int i = 0; i < 24; i += 4) {
        n0 = fmaf(rl(a, i    ), etr[i    ], n0);
        n1 = fmaf(rl(a, i + 1), etr[i + 1], n1);
        n2 = fmaf(rl(a, i + 2), etr[i + 2], n2);
        n3 = fmaf(rl(a, i + 3), etr[i + 3], n3);
    }
    n0 = fmaf(rl(a, 24), etr[24], n0);
    n1 = fmaf(rl(a, 25), etr[25], n1);
    return (n0 + n1) + (n2 + n3);
}

__global__ __launch_bounds__(256) void k_crf(const float* __restrict__ Eexp,
                                             const float* __restrict__ start_t,
                                             const float* __restrict__ end_t,
                                             const float* __restrict__ trans,
                                             const int* __restrict__ labels,
                                             const int* __restrict__ lengths,
                                             float* __restrict__ llh) {
    __shared__ float El[Sn * Tn + 32];
    __shared__ float comm[2];
    const int tid = threadIdx.x;
    const int b   = blockIdx.x;
    const int len = lengths[b];

    // ---- stage Eexp[b] (packed to stride 26) into LDS ----
    const float* src = Eexp + (size_t)b * Sn * TP;
    for (int id = tid; id < 4096; id += 256) {
        int s = id >> 3, c0 = (id & 7) * 4;
        if (c0 >= 28) continue;
        float4 vv = *reinterpret_cast<const float4*>(src + (size_t)s * TP + c0);
        float* p = El + s * Tn + c0;
        if (c0 < 24) { p[0] = vv.x; p[1] = vv.y; p[2] = vv.z; p[3] = vv.w; }
        else         { p[0] = vv.x; p[1] = vv.y; }
    }
    __syncthreads();

    const int lane = tid & 63;
    const int w    = tid >> 6;

    if (w == 0) {
        // ---- forward scan, linear space ----
        const int t = lane;
        const bool val = t < Tn;
        const int tc = val ? t : 0;
        float etr[Tn];
#pragma unroll
        for (int i = 0; i < Tn; ++i)
            etr[i] = val ? __expf(trans[i * Tn + t]) : 0.f;

        float a = val ? __expf(start_t[t]) * El[t] : 0.f;
        float logZ = 0.f;
        int rem = len - 1;
        int s = 1;
        float eem = El[Tn + tc];
        while (rem >= 4) {
#pragma unroll
            for (int u = 0; u < 4; ++u) {
                float na = matvec26(a, etr);
                ++s;
                a = na * eem;
                eem = El[s * Tn + tc];
            }
            float C = __uint_as_float(__builtin_amdgcn_readfirstlane(__float_as_uint(a)));
            a *= (1.0f / C);
            logZ += __logf(C);
            rem -= 4;
        }
        while (rem > 0) {
            float na = matvec26(a, etr);
            ++s;
            a = na * eem;
            eem = El[s * Tn + tc];
            --rem;
        }
        float av = val ? a * __expf(end_t[t]) : 0.f;
#pragma unroll
        for (int off = 32; off; off >>= 1) av += __shfl_xor(av, off);
        if (lane == 0) comm[0] = logZ + __logf(av);
    } else if (w == 1) {
        // ---- numerator (gold path) ----
        const int base = b * Sn;
        float part = 0.f;
        for (int s2 = 1 + lane; s2 < len; s2 += 64) {
            int lp = labels[base + s2 - 1];
            int lc = labels[base + s2];
            part += trans[lp * Tn + lc] + __logf(El[s2 * Tn + lc]);
        }
#pragma unroll
        for (int off = 32; off; off >>= 1) part += __shfl_xor(part, off);
        if (lane == 0) {
            int l0 = labels[base];
            int ll = labels[base + len - 1];
            comm[1] = part + start_t[l0] + __logf(El[l0]) + end_t[ll];
        }
    }
    __syncthreads();
    if (tid == 0) llh[b] = comm[1] - comm[0];
}

// ---------------- Kernel D: out = -mean(llh) ----------------
__global__ __launch_bounds__(64) void k_out(const float* __restrict__ llh,
                                            float* __restrict__ out) {
    float v = llh[threadIdx.x];
#pragma unroll
    for (int off = 32; off; off >>= 1) v += __shfl_xor(v, off);
    if (threadIdx.x == 0) out[0] = -v * (1.0f / 64.0f);
}

extern "C" void kernel_launch(void* const* d_in, const int* in_sizes, int n_in,
                              void* d_out, int out_size, void* d_ws, size_t ws_size,
                              hipStream_t stream) {
    const float* hidden  = (const float*)d_in[0];
    const float* W1      = (const float*)d_in[1];
    const float* b1      = (const float*)d_in[2];
    const float* W2      = (const float*)d_in[3];
    const float* b2      = (const float*)d_in[4];
    const float* start_t = (const float*)d_in[5];
    const float* end_t   = (const float*)d_in[6];
    const float* trans   = (const float*)d_in[7];
    const int*   labels  = (const int*)d_in[8];
    const int*   lengths = (const int*)d_in[9];
    float* ws  = (float*)d_ws;
    float* out = (float*)d_out;

    hipLaunchKernelGGL(k_prep, dim3(96), dim3(256), 0, stream, W1, b1, W2, b2, ws);
    hipLaunchKernelGGL(k_emis, dim3(256), dim3(256), 0, stream, hidden, ws, ws + OFF_EX);
    hipLaunchKernelGGL(k_crf, dim3(64), dim3(256), 0, stream, ws + OFF_EX, start_t, end_t,
                       trans, labels, lengths, ws + OFF_LLH);
    hipLaunchKernelGGL(k_out, dim3(1), dim3(64), 0, stream, ws + OFF_LLH, out);
}

// Round 3
// 128.489 us; speedup vs baseline: 2.1256x; 1.4302x over previous
//
#include <hip/hip_runtime.h>
#include <math.h>

#define Bn 64
#define Sn 512
#define Hn 768
#define Mn 512
#define Tn 26
#define TP 32   // padded tag dim in global Eexp

// ws layout (float units)
#define OFF_BC    0                         // bc[32]
#define OFF_BFRAG 32                        // 24576 bf16 (short) = 12288 floats
#define OFF_EX    (32 + 12288)              // Eexp[b][s][32] f32
#define EXSZ      ((size_t)Bn*Sn*TP)
#define OFF_LLH   (OFF_EX + EXSZ)           // llh[64]

typedef __attribute__((ext_vector_type(8))) short bfrag;
typedef __attribute__((ext_vector_type(4))) float f32x4;

__device__ __forceinline__ short f2bf(float f) {   // RNE float->bf16 bits
    unsigned u = __float_as_uint(f);
    unsigned r = (u + 0x7FFFu + ((u >> 16) & 1u)) >> 16;
    return (short)r;
}

// ---------------- Kernel A: Bfrag = bf16(W2@W1) in MFMA B-fragment order; bc ----------------
// frag element (ks, ct, lane, j): k = ks*32 + (lane>>4)*8 + j, col = ct*16 + (lane&15)
// flat idx = ((ks*2+ct)*64 + lane)*8 + j ; 24 ks * 2 ct * 64 * 8 = 24576 elems
__global__ __launch_bounds__(256) void k_prep(const float* __restrict__ W1,
                                              const float* __restrict__ b1,
                                              const float* __restrict__ W2,
                                              const float* __restrict__ b2,
                                              float* __restrict__ ws) {
    int fid = blockIdx.x * 256 + threadIdx.x;      // 96 blocks
    int j    = fid & 7;
    int lane = (fid >> 3) & 63;
    int ct   = (fid >> 9) & 1;
    int ks   = fid >> 10;
    int k    = ks * 32 + ((lane >> 4) & 3) * 8 + j;
    int col  = ct * 16 + (lane & 15);
    float acc = 0.f;
    if (col < Tn) {
        for (int m = 0; m < Mn; ++m)
            acc = fmaf(W2[col * Mn + m], W1[(size_t)m * Hn + k], acc);
    }
    ((unsigned short*)(ws + OFF_BFRAG))[fid] = (unsigned short)f2bf(acc);

    if (fid < TP) {
        float bcv = 0.f;
        if (fid < Tn) {
            bcv = b2[fid];
            for (int m = 0; m < Mn; ++m) bcv = fmaf(W2[fid * Mn + m], b1[m], bcv);
        }
        ws[OFF_BC + fid] = bcv;
    }
}

// ---------------- Kernel B: Eexp = exp(hidden @ Wc^T + bc) via bf16 MFMA ----------------
// 2048 blocks x 128 threads; block = 16-row tile; 2 waves split K (384 each), LDS merge.
__global__ __launch_bounds__(128) void k_gemm(const float* __restrict__ hidden,
                                              const float* __restrict__ ws,
                                              float* __restrict__ Eexp) {
    __shared__ float mrg[64 * 8];
    const int tid  = threadIdx.x;
    const int l    = tid & 63;
    const int h    = tid >> 6;                 // K-half 0/1
    const int row0 = blockIdx.x * 16;
    const int arow = row0 + (l & 15);
    const int kg   = l >> 4;                   // 0..3
    const float* abase = hidden + (size_t)arow * Hn + kg * 8;
    const unsigned short* Bf = (const unsigned short*)(ws + OFF_BFRAG);

    f32x4 acc0 = {0.f, 0.f, 0.f, 0.f}, acc1 = {0.f, 0.f, 0.f, 0.f};

    for (int kc = 0; kc < 3; ++kc) {
        const int ks0 = h * 12 + kc * 4;
        bfrag bv0[4], bv1[4];
#pragma unroll
        for (int ks = 0; ks < 4; ++ks) {
            bv0[ks] = *reinterpret_cast<const bfrag*>(Bf + ((size_t)((ks0 + ks) * 2 + 0) * 64 + l) * 8);
            bv1[ks] = *reinterpret_cast<const bfrag*>(Bf + ((size_t)((ks0 + ks) * 2 + 1) * 64 + l) * 8);
        }
#pragma unroll
        for (int ks = 0; ks < 4; ++ks) {
            const float* ap = abase + (ks0 + ks) * 32;
            float4 fa = *reinterpret_cast<const float4*>(ap);
            float4 fb = *reinterpret_cast<const float4*>(ap + 4);
            bfrag av;
            av[0] = f2bf(fa.x); av[1] = f2bf(fa.y); av[2] = f2bf(fa.z); av[3] = f2bf(fa.w);
            av[4] = f2bf(fb.x); av[5] = f2bf(fb.y); av[6] = f2bf(fb.z); av[7] = f2bf(fb.w);
            acc0 = __builtin_amdgcn_mfma_f32_16x16x32_bf16(av, bv0[ks], acc0, 0, 0, 0);
            acc1 = __builtin_amdgcn_mfma_f32_16x16x32_bf16(av, bv1[ks], acc1, 0, 0, 0);
        }
    }

    if (h == 1) {
#pragma unroll
        for (int i = 0; i < 4; ++i) { mrg[l * 8 + i] = acc0[i]; mrg[l * 8 + 4 + i] = acc1[i]; }
    }
    __syncthreads();
    if (h == 0) {
        const int c0 = l & 15;
        const int rbase = row0 + (l >> 4) * 4;
        float b0 = ws[OFF_BC + c0], b1v = ws[OFF_BC + 16 + c0];
#pragma unroll
        for (int i = 0; i < 4; ++i) {
            float v0 = acc0[i] + mrg[l * 8 + i]     + b0;
            float v1 = acc1[i] + mrg[l * 8 + 4 + i] + b1v;
            Eexp[(size_t)(rbase + i) * TP + c0]      = __expf(v0);
            Eexp[(size_t)(rbase + i) * TP + 16 + c0] = __expf(v1);
        }
    }
}

// ---------------- Kernel C: per-batch CRF (linear-space scan, LDS-staged) ----------------
__device__ __forceinline__ float rl(float x, int i) {
    return __uint_as_float(__builtin_amdgcn_readlane(__float_as_uint(x), i));
}
__device__ __forceinline__ float matvec26(float a, const float* etr) {
    float n0 = 0.f, n1 = 0.f, n2 = 0.f, n3 = 0.f;
#pragma unroll
    for (int i = 0; i < 24; i += 4) {
        n0 = fmaf(rl(a, i    ), etr[i    ], n0);
        n1 = fmaf(rl(a, i + 1), etr[i + 1], n1);
        n2 = fmaf(rl(a, i + 2), etr[i + 2], n2);
        n3 = fmaf(rl(a, i + 3), etr[i + 3], n3);
    }
    n0 = fmaf(rl(a, 24), etr[24], n0);
    n1 = fmaf(rl(a, 25), etr[25], n1);
    return (n0 + n1) + (n2 + n3);
}

__global__ __launch_bounds__(256) void k_crf(const float* __restrict__ Eexp,
                                             const float* __restrict__ start_t,
                                             const float* __restrict__ end_t,
                                             const float* __restrict__ trans,
                                             const int* __restrict__ labels,
                                             const int* __restrict__ lengths,
                                             float* __restrict__ llh) {
    __shared__ float El[Sn * Tn + 32];
    __shared__ float comm[2];
    const int tid = threadIdx.x;
    const int b   = blockIdx.x;
    const int len = lengths[b];

    // ---- stage Eexp[b] (packed to stride 26) into LDS ----
    const float* src = Eexp + (size_t)b * Sn * TP;
    for (int id = tid; id < 4096; id += 256) {
        int s = id >> 3, c0 = (id & 7) * 4;
        if (c0 >= 28) continue;
        float4 vv = *reinterpret_cast<const float4*>(src + (size_t)s * TP + c0);
        float* p = El + s * Tn + c0;
        if (c0 < 24) { p[0] = vv.x; p[1] = vv.y; p[2] = vv.z; p[3] = vv.w; }
        else         { p[0] = vv.x; p[1] = vv.y; }
    }
    __syncthreads();

    const int lane = tid & 63;
    const int w    = tid >> 6;

    if (w == 0) {
        // ---- forward scan, linear space ----
        const int t = lane;
        const bool val = t < Tn;
        const int tc = val ? t : 0;
        float etr[Tn];
#pragma unroll
        for (int i = 0; i < Tn; ++i)
            etr[i] = val ? __expf(trans[i * Tn + t]) : 0.f;

        float a = val ? __expf(start_t[t]) * El[t] : 0.f;
        float logZ = 0.f;
        int rem = len - 1;
        int s = 1;
        float eem = El[Tn + tc];
        while (rem >= 4) {
#pragma unroll
            for (int u = 0; u < 4; ++u) {
                float na = matvec26(a, etr);
                ++s;
                a = na * eem;
                eem = El[s * Tn + tc];
            }
            float C = __uint_as_float(__builtin_amdgcn_readfirstlane(__float_as_uint(a)));
            a *= (1.0f / C);
            logZ += __logf(C);
            rem -= 4;
        }
        while (rem > 0) {
            float na = matvec26(a, etr);
            ++s;
            a = na * eem;
            eem = El[s * Tn + tc];
            --rem;
        }
        float av = val ? a * __expf(end_t[t]) : 0.f;
#pragma unroll
        for (int off = 32; off; off >>= 1) av += __shfl_xor(av, off);
        if (lane == 0) comm[0] = logZ + __logf(av);
    } else if (w == 1) {
        // ---- numerator (gold path) ----
        const int base = b * Sn;
        float part = 0.f;
        for (int s2 = 1 + lane; s2 < len; s2 += 64) {
            int lp = labels[base + s2 - 1];
            int lc = labels[base + s2];
            part += trans[lp * Tn + lc] + __logf(El[s2 * Tn + lc]);
        }
#pragma unroll
        for (int off = 32; off; off >>= 1) part += __shfl_xor(part, off);
        if (lane == 0) {
            int l0 = labels[base];
            int ll = labels[base + len - 1];
            comm[1] = part + start_t[l0] + __logf(El[l0]) + end_t[ll];
        }
    }
    __syncthreads();
    if (tid == 0) llh[b] = comm[1] - comm[0];
}

// ---------------- Kernel D: out = -mean(llh) ----------------
__global__ __launch_bounds__(64) void k_out(const float* __restrict__ llh,
                                            float* __restrict__ out) {
    float v = llh[threadIdx.x];
#pragma unroll
    for (int off = 32; off; off >>= 1) v += __shfl_xor(v, off);
    if (threadIdx.x == 0) out[0] = -v * (1.0f / 64.0f);
}

extern "C" void kernel_launch(void* const* d_in, const int* in_sizes, int n_in,
                              void* d_out, int out_size, void* d_ws, size_t ws_size,
                              hipStream_t stream) {
    const float* hidden  = (const float*)d_in[0];
    const float* W1      = (const float*)d_in[1];
    const float* b1      = (const float*)d_in[2];
    const float* W2      = (const float*)d_in[3];
    const float* b2      = (const float*)d_in[4];
    const float* start_t = (const float*)d_in[5];
    const float* end_t   = (const float*)d_in[6];
    const float* trans   = (const float*)d_in[7];
    const int*   labels  = (const int*)d_in[8];
    const int*   lengths = (const int*)d_in[9];
    float* ws  = (float*)d_ws;
    float* out = (float*)d_out;

    hipLaunchKernelGGL(k_prep, dim3(96), dim3(256), 0, stream, W1, b1, W2, b2, ws);
    hipLaunchKernelGGL(k_gemm, dim3(2048), dim3(128), 0, stream, hidden, ws, ws + OFF_EX);
    hipLaunchKernelGGL(k_crf, dim3(64), dim3(256), 0, stream, ws + OFF_EX, start_t, end_t,
                       trans, labels, lengths, ws + OFF_LLH);
    hipLaunchKernelGGL(k_out, dim3(1), dim3(64), 0, stream, ws + OFF_LLH, out);
}

// Round 4
// 82.352 us; speedup vs baseline: 3.3164x; 1.5602x over previous
//
#include <hip/hip_runtime.h>
#include <math.h>

#define Bn 64
#define Sn 512
#define Hn 768
#define Mn 512
#define Tn 26
#define TP 32   // padded tag dim in global Eexp

// ws layout (float units)
#define OFF_BC    0                         // bc[32]
#define OFF_BFRAG 32                        // 24576 bf16 (short) = 12288 floats
#define OFF_EX    (32 + 12288)              // Eexp[b][s][32] f32
#define EXSZ      ((size_t)Bn*Sn*TP)        // 1048576
#define OFF_Q     (OFF_EX + EXSZ)           // Q[b][16][32 rows][36] f32
#define QSZ       ((size_t)1024*1152)       // 1179648
#define OFF_LLH   (OFF_Q + QSZ)             // llh[64]

typedef __attribute__((ext_vector_type(8)))  short bfrag;
typedef __attribute__((ext_vector_type(4)))  float f32x4;
typedef __attribute__((ext_vector_type(16))) float f32x16;

__device__ __forceinline__ short f2bf(float f) {   // RNE float->bf16 bits
    unsigned u = __float_as_uint(f);
    unsigned r = (u + 0x7FFFu + ((u >> 16) & 1u)) >> 16;
    return (short)r;
}
__device__ __forceinline__ unsigned cvtpk(float a, float b) {
    unsigned r;
    asm("v_cvt_pk_bf16_f32 %0, %1, %2" : "=v"(r) : "v"(a), "v"(b));
    return r;
}
__device__ __forceinline__ void pswap(unsigned &a, unsigned &b) {
    asm("v_permlane32_swap_b32 %0, %1" : "+v"(a), "+v"(b));
}
__device__ __forceinline__ bfrag mkfrag(unsigned a, unsigned b, unsigned c, unsigned d) {
    union { unsigned u[4]; bfrag v; } x;
    x.u[0] = a; x.u[1] = b; x.u[2] = c; x.u[3] = d;
    return x.v;
}
__device__ __forceinline__ float rl(float x, int i) {
    return __uint_as_float(__builtin_amdgcn_readlane(__float_as_uint(x), i));
}

// ---------------- Kernel A: Bfrag = bf16(W2@W1) in MFMA B-fragment order; bc ----------------
__global__ __launch_bounds__(256) void k_prep(const float* __restrict__ W1,
                                              const float* __restrict__ b1,
                                              const float* __restrict__ W2,
                                              const float* __restrict__ b2,
                                              float* __restrict__ ws) {
    int fid = blockIdx.x * 256 + threadIdx.x;      // 96 blocks
    int j    = fid & 7;
    int lane = (fid >> 3) & 63;
    int ct   = (fid >> 9) & 1;
    int ks   = fid >> 10;
    int k    = ks * 32 + ((lane >> 4) & 3) * 8 + j;
    int col  = ct * 16 + (lane & 15);
    float acc = 0.f;
    if (col < Tn) {
        for (int m = 0; m < Mn; ++m)
            acc = fmaf(W2[col * Mn + m], W1[(size_t)m * Hn + k], acc);
    }
    ((unsigned short*)(ws + OFF_BFRAG))[fid] = (unsigned short)f2bf(acc);

    if (fid < TP) {
        float bcv = 0.f;
        if (fid < Tn) {
            bcv = b2[fid];
            for (int m = 0; m < Mn; ++m) bcv = fmaf(W2[fid * Mn + m], b1[m], bcv);
        }
        ws[OFF_BC + fid] = bcv;
    }
}

// ---------------- Kernel B: Eexp = exp(hidden @ Wc^T + bc) via bf16 MFMA ----------------
__global__ __launch_bounds__(128) void k_gemm(const float* __restrict__ hidden,
                                              const float* __restrict__ ws,
                                              float* __restrict__ Eexp) {
    __shared__ float mrg[64 * 8];
    const int tid  = threadIdx.x;
    const int l    = tid & 63;
    const int h    = tid >> 6;                 // K-half 0/1
    const int row0 = blockIdx.x * 16;
    const int arow = row0 + (l & 15);
    const int kg   = l >> 4;                   // 0..3
    const float* abase = hidden + (size_t)arow * Hn + kg * 8;
    const unsigned short* Bf = (const unsigned short*)(ws + OFF_BFRAG);

    f32x4 acc0 = {0.f, 0.f, 0.f, 0.f}, acc1 = {0.f, 0.f, 0.f, 0.f};

    for (int kc = 0; kc < 3; ++kc) {
        const int ks0 = h * 12 + kc * 4;
        bfrag bv0[4], bv1[4];
#pragma unroll
        for (int ks = 0; ks < 4; ++ks) {
            bv0[ks] = *reinterpret_cast<const bfrag*>(Bf + ((size_t)((ks0 + ks) * 2 + 0) * 64 + l) * 8);
            bv1[ks] = *reinterpret_cast<const bfrag*>(Bf + ((size_t)((ks0 + ks) * 2 + 1) * 64 + l) * 8);
        }
#pragma unroll
        for (int ks = 0; ks < 4; ++ks) {
            const float* ap = abase + (ks0 + ks) * 32;
            float4 fa = *reinterpret_cast<const float4*>(ap);
            float4 fb = *reinterpret_cast<const float4*>(ap + 4);
            bfrag av;
            av[0] = f2bf(fa.x); av[1] = f2bf(fa.y); av[2] = f2bf(fa.z); av[3] = f2bf(fa.w);
            av[4] = f2bf(fb.x); av[5] = f2bf(fb.y); av[6] = f2bf(fb.z); av[7] = f2bf(fb.w);
            acc0 = __builtin_amdgcn_mfma_f32_16x16x32_bf16(av, bv0[ks], acc0, 0, 0, 0);
            acc1 = __builtin_amdgcn_mfma_f32_16x16x32_bf16(av, bv1[ks], acc1, 0, 0, 0);
        }
    }

    if (h == 1) {
#pragma unroll
        for (int i = 0; i < 4; ++i) { mrg[l * 8 + i] = acc0[i]; mrg[l * 8 + 4 + i] = acc1[i]; }
    }
    __syncthreads();
    if (h == 0) {
        const int c0 = l & 15;
        const int rbase = row0 + (l >> 4) * 4;
        float b0 = ws[OFF_BC + c0], b1v = ws[OFF_BC + 16 + c0];
#pragma unroll
        for (int i = 0; i < 4; ++i) {
            float v0 = acc0[i] + mrg[l * 8 + i]     + b0;
            float v1 = acc1[i] + mrg[l * 8 + 4 + i] + b1v;
            Eexp[(size_t)(rbase + i) * TP + c0]      = __expf(v0);
            Eexp[(size_t)(rbase + i) * TP + 16 + c0] = __expf(v1);
        }
    }
}

// ---------------- Kernel C1: chunked transition-matrix products via MFMA ----------------
// block (b, c): Q_chunk = Prod_{j=nact-1..0} [ diag(e_{s0+1+j}) * (etr^T/32) ]  (32x32, f32 out)
// grid 1024 = 64 batches x 16 chunks, 64 threads (1 wave).
__global__ __launch_bounds__(64) void k_scan(const float* __restrict__ Eexp,
                                             const float* __restrict__ trans,
                                             const int* __restrict__ lengths,
                                             float* __restrict__ Qout) {
    __shared__ float Ech[32 * 32];
    __shared__ float trs[676];
    const int tid = threadIdx.x;
    const int b = blockIdx.x >> 4;
    const int c = blockIdx.x & 15;
    const int len = lengths[b];
    const int s0 = c * 32;
    int nact = len - 1 - s0;
    nact = nact < 0 ? 0 : (nact > 32 ? 32 : nact);

    for (int i = tid; i < 676; i += 64) trs[i] = trans[i];
    {
        int r = tid >> 1, hf = tid & 1;
        int s = s0 + 1 + r;
        if (s < Sn) {
            const float4* src = reinterpret_cast<const float4*>(Eexp + ((size_t)(b * Sn + s)) * TP + hf * 16);
            float4* dst = reinterpret_cast<float4*>(Ech + r * 32 + hf * 16);
            dst[0] = src[0]; dst[1] = src[1]; dst[2] = src[2]; dst[3] = src[3];
        }
    }
    __syncthreads();

    const int t = tid & 31;           // column (and A-row) index
    const int h = tid >> 5;           // half

    // A = etr^T / 32 (static); B starts as Identity
    bfrag A0, A1, B0, B1;
#pragma unroll
    for (int j = 0; j < 8; ++j) {
        int k0 = 8 * h + j, k1 = 16 + 8 * h + j;
        A0[j] = (t < Tn && k0 < Tn) ? f2bf(__expf(trs[k0 * Tn + t]) * 0.03125f) : (short)0;
        A1[j] = (t < Tn && k1 < Tn) ? f2bf(__expf(trs[k1 * Tn + t]) * 0.03125f) : (short)0;
        B0[j] = (k0 == t) ? (short)0x3F80 : (short)0;
        B1[j] = (k1 == t) ? (short)0x3F80 : (short)0;
    }

    float qf[16];
#pragma unroll
    for (int r = 0; r < 16; ++r) {
        int row = (r & 3) + 8 * (r >> 2) + 4 * h;
        qf[r] = (row == t) ? 1.f : 0.f;       // identity (covers nact==0)
    }

    for (int j = 0; j < nact; ++j) {
        const float4* eb = reinterpret_cast<const float4*>(Ech + j * 32 + 4 * h);
        float4 e0 = eb[0], e1 = eb[2], e2 = eb[4], e3 = eb[6];   // rows {4h+8g..+3}, broadcast
        f32x16 acc = {};
        acc = __builtin_amdgcn_mfma_f32_32x32x16_bf16(A0, B0, acc, 0, 0, 0);
        acc = __builtin_amdgcn_mfma_f32_32x32x16_bf16(A1, B1, acc, 0, 0, 0);
        float ev[16];
        ev[0] = e0.x; ev[1] = e0.y; ev[2]  = e0.z; ev[3]  = e0.w;
        ev[4] = e1.x; ev[5] = e1.y; ev[6]  = e1.z; ev[7]  = e1.w;
        ev[8] = e2.x; ev[9] = e2.y; ev[10] = e2.z; ev[11] = e2.w;
        ev[12] = e3.x; ev[13] = e3.y; ev[14] = e3.z; ev[15] = e3.w;
#pragma unroll
        for (int r = 0; r < 16; ++r) qf[r] = acc[r] * ev[r];
        if (j + 1 < nact) {
            // relayout C (f32, rows spread) -> next B-frags (bf16): cvt_pk pairs + half swaps
            unsigned W0 = cvtpk(qf[0],  qf[1]),  W1 = cvtpk(qf[2],  qf[3]);
            unsigned W2 = cvtpk(qf[4],  qf[5]),  W3 = cvtpk(qf[6],  qf[7]);
            unsigned W4 = cvtpk(qf[8],  qf[9]),  W5 = cvtpk(qf[10], qf[11]);
            unsigned W6 = cvtpk(qf[12], qf[13]), W7 = cvtpk(qf[14], qf[15]);
            pswap(W0, W2); pswap(W1, W3); pswap(W4, W6); pswap(W5, W7);
            B0 = mkfrag(W0, W1, W2, W3);
            B1 = mkfrag(W4, W5, W6, W7);
        }
    }

    float* qdst = Qout + (size_t)(b * 16 + c) * 1152;   // rows stride 36 (16B-aligned)
#pragma unroll
    for (int r = 0; r < 16; ++r) {
        int row = (r & 3) + 8 * (r >> 2) + 4 * h;
        qdst[row * 36 + t] = qf[r];
    }
}

// ---------------- Kernel C2: per-batch combine (16 chunk matvecs) + numerator ----------------
__global__ __launch_bounds__(128) void k_comb(const float* __restrict__ Eexp,
                                              const float* __restrict__ Qq,
                                              const float* __restrict__ start_t,
                                              const float* __restrict__ end_t,
                                              const float* __restrict__ trans,
                                              const int* __restrict__ labels,
                                              const int* __restrict__ lengths,
                                              float* __restrict__ llh) {
    __shared__ float comm[2];
    const int tid = threadIdx.x;
    const int b   = blockIdx.x;
    const int len = lengths[b];
    const int lane = tid & 63;
    const int w    = tid >> 6;

    if (w == 0) {
        const int t = lane & 31;
        float alpha = (t < Tn) ? __expf(start_t[t]) * Eexp[(size_t)b * Sn * TP + t] : 0.f;
        float logZ = 0.f;
        const float* qb = Qq + (size_t)b * 16 * 1152 + t * 36;
        float4 a0, a1, a2, a3, a4, a5, a6, a7;
        {
            const float4* p = reinterpret_cast<const float4*>(qb);
            a0 = p[0]; a1 = p[1]; a2 = p[2]; a3 = p[3];
            a4 = p[4]; a5 = p[5]; a6 = p[6]; a7 = p[7];
        }
        for (int c = 0; c < 16; ++c) {
            float4 b0 = a0, b1 = a1, b2 = a2, b3 = a3, b4 = a4, b5 = a5, b6 = a6, b7 = a7;
            if (c < 15) {
                const float4* p = reinterpret_cast<const float4*>(qb + (size_t)(c + 1) * 1152);
                b0 = p[0]; b1 = p[1]; b2 = p[2]; b3 = p[3];
                b4 = p[4]; b5 = p[5]; b6 = p[6]; b7 = p[7];
            }
            float qv[32];
            qv[0] = a0.x; qv[1] = a0.y; qv[2] = a0.z; qv[3] = a0.w;
            qv[4] = a1.x; qv[5] = a1.y; qv[6] = a1.z; qv[7] = a1.w;
            qv[8] = a2.x; qv[9] = a2.y; qv[10] = a2.z; qv[11] = a2.w;
            qv[12] = a3.x; qv[13] = a3.y; qv[14] = a3.z; qv[15] = a3.w;
            qv[16] = a4.x; qv[17] = a4.y; qv[18] = a4.z; qv[19] = a4.w;
            qv[20] = a5.x; qv[21] = a5.y; qv[22] = a5.z; qv[23] = a5.w;
            qv[24] = a6.x; qv[25] = a6.y; qv[26] = a6.z; qv[27] = a6.w;
            qv[28] = a7.x; qv[29] = a7.y; qv[30] = a7.z; qv[31] = a7.w;
            float p0 = 0.f, p1 = 0.f, p2 = 0.f, p3 = 0.f;
#pragma unroll
            for (int i = 0; i < 32; i += 4) {
                p0 = fmaf(rl(alpha, i + 0), qv[i + 0], p0);
                p1 = fmaf(rl(alpha, i + 1), qv[i + 1], p1);
                p2 = fmaf(rl(alpha, i + 2), qv[i + 2], p2);
                p3 = fmaf(rl(alpha, i + 3), qv[i + 3], p3);
            }
            float v = (p0 + p1) + (p2 + p3);
            float C = __uint_as_float(__builtin_amdgcn_readfirstlane(__float_as_uint(v)));
            alpha = v / C;
            logZ += __logf(C);
            a0 = b0; a1 = b1; a2 = b2; a3 = b3; a4 = b4; a5 = b5; a6 = b6; a7 = b7;
        }
        float dv = (t < Tn && lane < 32) ? alpha * __expf(end_t[t]) : 0.f;
#pragma unroll
        for (int off = 32; off; off >>= 1) dv += __shfl_xor(dv, off);
        if (lane == 0) comm[0] = logZ + __logf(dv) + (float)(len - 1) * 3.46573590279973f;
    } else {
        const int base = b * Sn;
        const float* Eb = Eexp + (size_t)base * TP;
        float part = 0.f;
        for (int s2 = 1 + lane; s2 < len; s2 += 64) {
            int lp = labels[base + s2 - 1];
            int lc = labels[base + s2];
            part += trans[lp * Tn + lc] + __logf(Eb[(size_t)s2 * TP + lc]);
        }
#pragma unroll
        for (int off = 32; off; off >>= 1) part += __shfl_xor(part, off);
        if (lane == 0) {
            int l0 = labels[base];
            int ll = labels[base + len - 1];
            comm[1] = part + start_t[l0] + __logf(Eb[l0]) + end_t[ll];
        }
    }
    __syncthreads();
    if (tid == 0) llh[b] = comm[1] - comm[0];
}

// ---------------- Kernel D: out = -mean(llh) ----------------
__global__ __launch_bounds__(64) void k_out(const float* __restrict__ llh,
                                            float* __restrict__ out) {
    float v = llh[threadIdx.x];
#pragma unroll
    for (int off = 32; off; off >>= 1) v += __shfl_xor(v, off);
    if (threadIdx.x == 0) out[0] = -v * (1.0f / 64.0f);
}

extern "C" void kernel_launch(void* const* d_in, const int* in_sizes, int n_in,
                              void* d_out, int out_size, void* d_ws, size_t ws_size,
                              hipStream_t stream) {
    const float* hidden  = (const float*)d_in[0];
    const float* W1      = (const float*)d_in[1];
    const float* b1      = (const float*)d_in[2];
    const float* W2      = (const float*)d_in[3];
    const float* b2      = (const float*)d_in[4];
    const float* start_t = (const float*)d_in[5];
    const float* end_t   = (const float*)d_in[6];
    const float* trans   = (const float*)d_in[7];
    const int*   labels  = (const int*)d_in[8];
    const int*   lengths = (const int*)d_in[9];
    float* ws  = (float*)d_ws;
    float* out = (float*)d_out;

    hipLaunchKernelGGL(k_prep, dim3(96), dim3(256), 0, stream, W1, b1, W2, b2, ws);
    hipLaunchKernelGGL(k_gemm, dim3(2048), dim3(128), 0, stream, hidden, ws, ws + OFF_EX);
    hipLaunchKernelGGL(k_scan, dim3(1024), dim3(64), 0, stream, ws + OFF_EX, trans, lengths,
                       ws + OFF_Q);
    hipLaunchKernelGGL(k_comb, dim3(64), dim3(128), 0, stream, ws + OFF_EX, ws + OFF_Q,
                       start_t, end_t, trans, labels, lengths, ws + OFF_LLH);
    hipLaunchKernelGGL(k_out, dim3(1), dim3(64), 0, stream, ws + OFF_LLH, out);
}